// Round 1
// baseline (16634.648 us; speedup 1.0000x reference)
//
#include <hip/hip_runtime.h>
#include <math.h>

// ---------------------------------------------------------------------------
// PhyRNN: 2-layer LSTM (B=64, T=3000, I=8, H=128) + FC head + double FD deriv.
//
// Structure:
//  K1 lstm_layer0 : 64 WGs (1 per batch), 512 thr (1 gate row each, W row in
//                   128 VGPRs). Serial t-loop; h broadcast via LDS. Writes h1.
//  K2 lstm_layer1 : same, but input projection W_ih1@h1_t (K=128) is computed
//                   in a parallel per-chunk phase (CHUNK=24 steps) into LDS,
//                   keeping the serial recurrence at K=128. h2 overwrites h1
//                   in place (phase A of a chunk reads h1 before phase B
//                   writes h2 for the same t range).
//  K3 fc_head     : per-(b,t) thread: 128->16->4->1 with ReLU. Writes y[t][b].
//  K4/K5 deriv_k  : phi is a banded FD operator -> 3-tap stencil, applied
//                   twice. Final write transposed to out[b][t].
//
// Precision: everything fp32 (no fp32 MFMA on CDNA4; bf16 too risky because
// the double derivative amplifies per-element noise by ~1e3).
// ws: h buffer 98.304 MB + y 0.768 MB + z 0.768 MB  (~99.85 MB total).
// ---------------------------------------------------------------------------

#define T_STEPS 3000
#define BATCH   64
#define HID     128
#define GATES   512
#define CHUNK   24      // 3000 = 125 * 24 exactly; xp LDS = 24*512*4 = 48 KB
#define INV_DT  50.0f   // 1/0.02

__device__ __forceinline__ float sigmoid_(float x) {
    return 1.0f / (1.0f + __expf(-x));
}
__device__ __forceinline__ float tanh_(float x) {
    // 1 - 2/(e^{2x}+1): correct limits at +/-inf via exp overflow/underflow
    return 1.0f - 2.0f / (__expf(2.0f * x) + 1.0f);
}

// ---------------------------------------------------------------- layer 0 ---
__global__ __launch_bounds__(512, 2)
void lstm_layer0(const float* __restrict__ x,      // [64][3000][8]
                 const float* __restrict__ w_ih,   // [512][8]
                 const float* __restrict__ w_hh,   // [512][128]
                 const float* __restrict__ b_ih,
                 const float* __restrict__ b_hh,
                 float* __restrict__ h_out)        // [64][3000][128]
{
    const int b = blockIdx.x;
    const int g = threadIdx.x;              // gate row 0..511 (i,f,g,o blocks)
    const int j = g & (HID - 1);

    __shared__ __align__(16) float h_s[HID];
    __shared__ float part_f[HID], part_g[HID], part_o[HID];

    // W_hh row in registers (static indexing only -> stays in VGPRs)
    float w[HID];
#pragma unroll
    for (int i = 0; i < HID; i += 4) {
        float4 v = *(const float4*)(w_hh + (size_t)g * HID + i);
        w[i] = v.x; w[i+1] = v.y; w[i+2] = v.z; w[i+3] = v.w;
    }
    float wi[8];
#pragma unroll
    for (int i = 0; i < 8; i += 4) {
        float4 v = *(const float4*)(w_ih + (size_t)g * 8 + i);
        wi[i] = v.x; wi[i+1] = v.y; wi[i+2] = v.z; wi[i+3] = v.w;
    }
    const float bias = b_ih[g] + b_hh[g];
    float c = 0.0f;                          // cell state (owned by g<128)

    if (g < HID) h_s[g] = 0.0f;
    __syncthreads();

    const float* xrow = x + (size_t)b * T_STEPS * 8;
    float* hb = h_out + (size_t)b * T_STEPS * HID;

    for (int t = 0; t < T_STEPS; ++t) {
        // input projection (I=8, uniform-address loads, L1-hot)
        float4 xa = *(const float4*)(xrow + t * 8);
        float4 xc = *(const float4*)(xrow + t * 8 + 4);
        float acc = bias
                  + wi[0]*xa.x + wi[1]*xa.y + wi[2]*xa.z + wi[3]*xa.w
                  + wi[4]*xc.x + wi[5]*xc.y + wi[6]*xc.z + wi[7]*xc.w;
        // recurrent dot: h broadcast from LDS
#pragma unroll
        for (int k4 = 0; k4 < HID / 4; ++k4) {
            float4 h4 = *(const float4*)(&h_s[4 * k4]);
            acc += w[4*k4]*h4.x + w[4*k4+1]*h4.y + w[4*k4+2]*h4.z + w[4*k4+3]*h4.w;
        }

        float sig_i = 0.0f;
        if      (g < 128) sig_i    = sigmoid_(acc);   // i (kept in reg)
        else if (g < 256) part_f[j] = sigmoid_(acc);  // f
        else if (g < 384) part_g[j] = tanh_(acc);     // g
        else              part_o[j] = sigmoid_(acc);  // o
        __syncthreads();

        if (g < 128) {
            c = part_f[j] * c + sig_i * part_g[j];
            float h = part_o[j] * tanh_(c);
            h_s[j] = h;
            hb[(size_t)t * HID + j] = h;
        }
        __syncthreads();
    }
}

// ---------------------------------------------------------------- layer 1 ---
__global__ __launch_bounds__(512, 2)
void lstm_layer1(const float* __restrict__ w_ih,   // [512][128]
                 const float* __restrict__ w_hh,   // [512][128]
                 const float* __restrict__ b_ih,
                 const float* __restrict__ b_hh,
                 float* __restrict__ h_buf)        // in: h1, out: h2 (in place)
{
    const int b = blockIdx.x;
    const int g = threadIdx.x;
    const int j = g & (HID - 1);

    __shared__ __align__(16) float xp[CHUNK][GATES];   // 48 KB
    __shared__ __align__(16) float h_s[HID];
    __shared__ float part_f[HID], part_g[HID], part_o[HID];

    const float bias = b_ih[g] + b_hh[g];
    float c = 0.0f;
    if (g < HID) h_s[g] = 0.0f;

    float* hb = h_buf + (size_t)b * T_STEPS * HID;
    float w[HID];
    __syncthreads();

    for (int t0 = 0; t0 < T_STEPS; t0 += CHUNK) {
        // ---- load W_ih row (reloaded per chunk; L2-resident, cheap)
#pragma unroll
        for (int i = 0; i < HID; i += 4) {
            float4 v = *(const float4*)(w_ih + (size_t)g * HID + i);
            w[i] = v.x; w[i+1] = v.y; w[i+2] = v.z; w[i+3] = v.w;
        }
        // ---- phase A: xp[tau][g] = bias + W_ih[g] . h1[t0+tau]  (parallel)
        for (int tg = 0; tg < CHUNK; tg += 8) {
            float a[8];
#pragma unroll
            for (int i = 0; i < 8; ++i) a[i] = bias;
            const float* hp = hb + (size_t)(t0 + tg) * HID;
#pragma unroll
            for (int k4 = 0; k4 < HID / 4; ++k4) {
#pragma unroll
                for (int i = 0; i < 8; ++i) {
                    float4 h4 = *(const float4*)(hp + i * HID + 4 * k4);
                    a[i] += w[4*k4]*h4.x + w[4*k4+1]*h4.y
                          + w[4*k4+2]*h4.z + w[4*k4+3]*h4.w;
                }
            }
#pragma unroll
            for (int i = 0; i < 8; ++i) xp[tg + i][g] = a[i];
        }
        // ---- swap to W_hh row for the recurrence
#pragma unroll
        for (int i = 0; i < HID; i += 4) {
            float4 v = *(const float4*)(w_hh + (size_t)g * HID + i);
            w[i] = v.x; w[i+1] = v.y; w[i+2] = v.z; w[i+3] = v.w;
        }
        __syncthreads();   // xp visible; h1 chunk fully consumed

        // ---- phase B: serial recurrence over the chunk
        for (int tt = 0; tt < CHUNK; ++tt) {
            float acc = xp[tt][g];
#pragma unroll
            for (int k4 = 0; k4 < HID / 4; ++k4) {
                float4 h4 = *(const float4*)(&h_s[4 * k4]);
                acc += w[4*k4]*h4.x + w[4*k4+1]*h4.y + w[4*k4+2]*h4.z + w[4*k4+3]*h4.w;
            }
            float sig_i = 0.0f;
            if      (g < 128) sig_i    = sigmoid_(acc);
            else if (g < 256) part_f[j] = sigmoid_(acc);
            else if (g < 384) part_g[j] = tanh_(acc);
            else              part_o[j] = sigmoid_(acc);
            __syncthreads();
            if (g < 128) {
                c = part_f[j] * c + sig_i * part_g[j];
                float h = part_o[j] * tanh_(c);
                h_s[j] = h;
                hb[(size_t)(t0 + tt) * HID + j] = h;   // h2 overwrites h1
            }
            __syncthreads();
        }
    }
}

// ---------------------------------------------------------------- FC head ---
__global__ void fc_head(const float* __restrict__ h_buf,  // h2 [64][3000][128]
                        const float* __restrict__ fc1_w, const float* __restrict__ fc1_b,
                        const float* __restrict__ fc2_w, const float* __restrict__ fc2_b,
                        const float* __restrict__ fc3_w, const float* __restrict__ fc3_b,
                        float* __restrict__ y_t)          // [3000][64]
{
    int idx = blockIdx.x * blockDim.x + threadIdx.x;   // idx = t*64 + b
    if (idx >= T_STEPS * BATCH) return;
    int t = idx >> 6, b = idx & 63;

    const float* h = h_buf + (size_t)b * T_STEPS * HID + (size_t)t * HID;
    float hv[HID];
#pragma unroll
    for (int k = 0; k < HID; k += 4) {
        float4 v = *(const float4*)(h + k);
        hv[k] = v.x; hv[k+1] = v.y; hv[k+2] = v.z; hv[k+3] = v.w;
    }
    float y1[16];
#pragma unroll
    for (int jo = 0; jo < 16; ++jo) {
        float a = fc1_b[jo];
#pragma unroll
        for (int k = 0; k < HID; k += 4) {
            float4 wv = *(const float4*)(fc1_w + jo * HID + k);
            a += wv.x*hv[k] + wv.y*hv[k+1] + wv.z*hv[k+2] + wv.w*hv[k+3];
        }
        y1[jo] = fmaxf(a, 0.0f);
    }
    float y2[4];
#pragma unroll
    for (int jo = 0; jo < 4; ++jo) {
        float a = fc2_b[jo];
#pragma unroll
        for (int k = 0; k < 16; ++k) a += fc2_w[jo * 16 + k] * y1[k];
        y2[jo] = fmaxf(a, 0.0f);
    }
    float y = fc3_b[0];
#pragma unroll
    for (int k = 0; k < 4; ++k) y += fc3_w[k] * y2[k];

    y_t[idx] = y;   // coalesced: idx = t*64+b
}

// ------------------------------------------------------------- FD stencil ---
// phi row 0: (-1.5,2,-0.5)/dt ; rows 1..n-2: (-0.5,0,0.5)/dt ; row n-1: (0.5,-2,1.5)/dt
__global__ void deriv_k(const float* __restrict__ in,   // [3000][64]
                        float* __restrict__ outp,
                        int transpose_out)
{
    int idx = blockIdx.x * blockDim.x + threadIdx.x;
    if (idx >= T_STEPS * BATCH) return;
    int t = idx >> 6, b = idx & 63;
    float v;
    if (t == 0) {
        v = (-1.5f * in[b] + 2.0f * in[64 + b] - 0.5f * in[128 + b]) * INV_DT;
    } else if (t == T_STEPS - 1) {
        v = (0.5f * in[(t-2)*64 + b] - 2.0f * in[(t-1)*64 + b] + 1.5f * in[t*64 + b]) * INV_DT;
    } else {
        v = (in[(t+1)*64 + b] - in[(t-1)*64 + b]) * (0.5f * INV_DT);
    }
    if (transpose_out) outp[(size_t)b * T_STEPS + t] = v;   // final out[b][t]
    else               outp[idx] = v;
}

// ------------------------------------------------------------------ launch --
extern "C" void kernel_launch(void* const* d_in, const int* in_sizes, int n_in,
                              void* d_out, int out_size, void* d_ws, size_t ws_size,
                              hipStream_t stream)
{
    const float* x     = (const float*)d_in[0];
    const float* w_ih0 = (const float*)d_in[1];
    const float* w_hh0 = (const float*)d_in[2];
    const float* b_ih0 = (const float*)d_in[3];
    const float* b_hh0 = (const float*)d_in[4];
    const float* w_ih1 = (const float*)d_in[5];
    const float* w_hh1 = (const float*)d_in[6];
    const float* b_ih1 = (const float*)d_in[7];
    const float* b_hh1 = (const float*)d_in[8];
    const float* fc1_w = (const float*)d_in[9];
    const float* fc1_b = (const float*)d_in[10];
    const float* fc2_w = (const float*)d_in[11];
    const float* fc2_b = (const float*)d_in[12];
    const float* fc3_w = (const float*)d_in[13];
    const float* fc3_b = (const float*)d_in[14];
    float* out = (float*)d_out;

    // ws layout: h buffer (98.304 MB) | y (0.768 MB) | z (0.768 MB)
    float* h_buf = (float*)d_ws;
    float* y_t   = (float*)((char*)d_ws + 98304000);
    float* z_t   = (float*)((char*)d_ws + 98304000 + 768000);

    lstm_layer0<<<dim3(BATCH), dim3(512), 0, stream>>>(x, w_ih0, w_hh0, b_ih0, b_hh0, h_buf);
    lstm_layer1<<<dim3(BATCH), dim3(512), 0, stream>>>(w_ih1, w_hh1, b_ih1, b_hh1, h_buf);

    const int nelem = T_STEPS * BATCH;
    fc_head<<<dim3((nelem + 255) / 256), dim3(256), 0, stream>>>(
        h_buf, fc1_w, fc1_b, fc2_w, fc2_b, fc3_w, fc3_b, y_t);
    deriv_k<<<dim3((nelem + 255) / 256), dim3(256), 0, stream>>>(y_t, z_t, 0);
    deriv_k<<<dim3((nelem + 255) / 256), dim3(256), 0, stream>>>(z_t, out, 1);
}